// Round 6
// baseline (837.943 us; speedup 1.0000x reference)
//
#include <hip/hip_runtime.h>
#include <hip/hip_bf16.h>

// ---------------- problem constants ----------------
#define NN 20000      // nodes
#define EE 640000     // edges
#define RR 65         // relations
#define FIN1 128      // input feat
#define HH1 64        // hidden1
#define HH2 32        // hidden2
#define BB 8192       // pairs

constexpr int BM = 128;                 // edge-tile rows per GEMM block
constexpr int NBH = 256;                // histogram/placement blocks
constexpr int GRID_PRE = 2048;          // k_hist launch grid (occupancy for conversions)
constexpr int EPB = EE / NBH;           // 2500 edges per block
constexpr int NBT = (NN + BM - 1) / BM; // 157 node tiles
constexpr int NOCT = 8;                 // src octiles (nodes per octile = 2500)
constexpr int NPO = NN / NOCT;          // 2500
constexpr int NB2 = NOCT * RR;          // 520 sort buckets (octile-major, relation inner)
constexpr int MAXT2 = EE / BM + NB2;    // 5520 tile upper bound

// classifier GEMM geometry (E[8192x448] @ clsW[448x65], padded)
constexpr int CLS_K  = 512;
constexpr int CLS_N  = 80;
constexpr int CLS_CK = 128;
constexpr int CLS_BM = 64;

// fixed-point scale for deterministic atomic accumulation.
// |per-edge value| <~ 4, per-dst sum <~ 400  ->  400*2^20 ~ 2^28.6 << 2^31.
// quantization error ~ deg * 2^-21 ~ 3e-5, far below the 0.125 tolerance,
// and the bf16 msg rounding it replaces was coarser.
constexpr float FXS  = 1048576.0f;        // 2^20
constexpr float FXSI = 1.0f / 1048576.0f;

typedef __attribute__((ext_vector_type(8))) short short8;   // 8 bf16 MFMA frag
typedef __attribute__((ext_vector_type(4))) float floatx4;  // 4 fp32 acc

// ---------------- workspace layout (bytes) ----------------
constexpr size_t aln(size_t x) { return (x + 255) & ~(size_t)255; }

constexpr size_t OFF_CSUM  = 0;                        // 32 f
constexpr size_t OFF_CNTD  = aln(OFF_CSUM + 32 * 4);  // NN int (dst degree)
constexpr size_t ZERO_BYTES = OFF_CNTD + (size_t)NN * 4;   // memset [0, ZERO_BYTES)
constexpr size_t OFF_DSTOFF = aln(ZERO_BYTES);         // NN+1 int
constexpr size_t OFF_BH0   = aln(OFF_DSTOFF + ((size_t)NN + 1) * 4); // NBH*NB2
constexpr size_t OFF_BH1   = OFF_BH0 + (size_t)NBH * NB2 * 4;
constexpr size_t OFF_BB0   = OFF_BH1 + (size_t)NBH * NB2 * 4;
constexpr size_t OFF_BB1   = OFF_BB0 + (size_t)NBH * NB2 * 4;
constexpr size_t OFF_HT    = aln(OFF_BB1 + (size_t)NBH * NB2 * 4);   // 2*NB2 int totals
constexpr size_t OFF_OFFB0 = aln(OFF_HT + (size_t)2 * NB2 * 4);      // NB2+1 int
constexpr size_t OFF_OFFB1 = OFF_OFFB0 + (NB2 + 1) * 4;
constexpr size_t OFF_TILB0 = aln(OFF_OFFB1 + (NB2 + 1) * 4);  // MAXT2 int
constexpr size_t OFF_TILT0 = OFF_TILB0 + (size_t)MAXT2 * 4;
constexpr size_t OFF_TILB1 = OFF_TILT0 + (size_t)MAXT2 * 4;
constexpr size_t OFF_TILT1 = OFF_TILB1 + (size_t)MAXT2 * 4;
constexpr size_t OFF_SLOT  = aln(OFF_TILT1 + (size_t)MAXT2 * 4);  // E int
constexpr size_t OFF_POSD  = OFF_SLOT + (size_t)EE * 4;           // E int (e -> dst pos)
constexpr size_t OFF_RDP   = OFF_POSD + (size_t)EE * 4;           // E uint (pos -> r0|r1<<16)
constexpr size_t OFF_WD0   = OFF_RDP + (size_t)EE * 4;            // E float (pos-space weights)
constexpr size_t OFF_WD1   = OFF_WD0 + (size_t)EE * 4;
constexpr size_t OFF_PERM0 = OFF_WD1 + (size_t)EE * 4;            // E uint (srcLocal<<20|pos)
constexpr size_t OFF_PERM1 = OFF_PERM0 + (size_t)EE * 4;
constexpr size_t OFF_XOB   = aln(OFF_PERM1 + (size_t)EE * 4);     // N*F bf16
constexpr size_t OFF_XAB   = OFF_XOB + (size_t)NN * FIN1 * 2;
constexpr size_t OFF_H1    = aln(OFF_XAB + (size_t)NN * FIN1 * 2); // 3 * N*64 f
constexpr size_t OFF_H1B   = OFF_H1 + (size_t)3 * NN * HH1 * 4;    // 3 * N*64 bf16
constexpr size_t OFF_X2A   = OFF_H1B + (size_t)3 * NN * HH1 * 2;   // N*32 f
constexpr size_t OFF_X2AA  = OFF_X2A + (size_t)NN * HH2 * 4;
constexpr size_t OFF_W1BT  = OFF_X2AA + (size_t)NN * HH2 * 4;      // R*64*128 bf16
constexpr size_t OFF_W2BT  = OFF_W1BT + (size_t)RR * HH1 * FIN1 * 2;
constexpr size_t OFF_R1T   = OFF_W2BT + (size_t)RR * HH2 * HH1 * 2;
constexpr size_t OFF_R2T   = OFF_R1T + (size_t)HH1 * FIN1 * 2;
constexpr size_t OFF_CWT   = OFF_R2T + (size_t)HH2 * HH1 * 2;
constexpr size_t OFF_PART  = aln(OFF_CWT + (size_t)CLS_N * CLS_K * 2); // 256*32 f partials
// fixed-point accumulators (replace the old msg buffers; L2/L3-resident)
constexpr size_t OFF_ACC1  = aln(OFF_PART + (size_t)256 * 32 * 4);  // 3*N*64 int
constexpr size_t OFF_ACC2  = OFF_ACC1 + (size_t)3 * NN * HH1 * 4;   // 3*N*32 int
constexpr size_t OFF_DSTP  = OFF_ACC2 + (size_t)3 * NN * HH2 * 4;   // E int (pos -> dst)
constexpr size_t ACC_ZB    = (size_t)3 * NN * (HH1 + HH2) * 4;      // memset span

// output offsets (floats)
constexpr size_t O_LOG  = 0;
constexpr size_t O_ROS  = (size_t)BB * RR;
constexpr size_t O_ROSA = O_ROS + (size_t)NN * 2;
constexpr size_t O_X2O  = O_ROSA + (size_t)NN * 2;

__device__ inline unsigned short f2bf(float f) {
    __hip_bfloat16 h = __float2bfloat16(f);
    return *reinterpret_cast<unsigned short*>(&h);
}

// per-enc pointer bundle for merged gemm launches
struct GemmEnc {
    const unsigned short* X;
    int* acc;                      // fixed-point accumulator (N x HOUT)
    const unsigned int* perm;
    const int* offB;
    const int* tilB;
    const int* tilT;
    const float* wD;               // pos-space mean weights
};
struct GemmArgs { GemmEnc e[3]; };

struct Fin2P { float* o[3]; };

// ---------------- preprocessing ----------------
// blocks < NBH: per-block 520-bin (octile,relation) histograms via LDS,
// per-dst degree + slot. ALL blocks: vectorized streaming bf16 conversions.
__global__ void k_hist(const int* __restrict__ ei, const int* __restrict__ et0,
                       const int* __restrict__ et1,
                       int* cntD, int* __restrict__ slotE,
                       int* __restrict__ bh0, int* __restrict__ bh1,
                       const float* __restrict__ x_o, const float* __restrict__ x_a,
                       const float* __restrict__ W1, const float* __restrict__ W2,
                       const float* __restrict__ root1, const float* __restrict__ root2,
                       const float* __restrict__ clsW,
                       unsigned short* xob, unsigned short* xab,
                       unsigned short* w1t, unsigned short* w2t,
                       unsigned short* r1t, unsigned short* r2t,
                       unsigned short* cwt) {
    __shared__ int lh0[NB2], lh1[NB2];
    int t = threadIdx.x;
    if (blockIdx.x < NBH) {
        for (int p = t; p < NB2; p += 256) { lh0[p] = 0; lh1[p] = 0; }
        __syncthreads();
        int base = blockIdx.x * EPB;
        for (int i = t; i < EPB; i += 256) {
            int e = base + i;
            int oct = ei[e] / NPO;
            atomicAdd(&lh0[oct * RR + et0[e]], 1);
            atomicAdd(&lh1[oct * RR + et1[e]], 1);
            slotE[e] = atomicAdd(&cntD[ei[EE + e]], 1);
        }
        __syncthreads();
        for (int p = t; p < NB2; p += 256) {
            bh0[blockIdx.x * NB2 + p] = lh0[p];
            bh1[blockIdx.x * NB2 + p] = lh1[p];
        }
    }
    // streaming conversions (grid-stride, vectorized 4-wide)
    int stride = gridDim.x * 256;
    int i0 = blockIdx.x * 256 + t;
    const int NX4 = NN * FIN1 / 4;
    const float4* xo4 = (const float4*)x_o;
    const float4* xa4 = (const float4*)x_a;
    for (int i = i0; i < NX4; i += stride) {
        float4 a = xo4[i], b = xa4[i];
        uint2 pa, pb;
        pa.x = (unsigned)f2bf(a.x) | ((unsigned)f2bf(a.y) << 16);
        pa.y = (unsigned)f2bf(a.z) | ((unsigned)f2bf(a.w) << 16);
        pb.x = (unsigned)f2bf(b.x) | ((unsigned)f2bf(b.y) << 16);
        pb.y = (unsigned)f2bf(b.z) | ((unsigned)f2bf(b.w) << 16);
        ((uint2*)xob)[i] = pa;
        ((uint2*)xab)[i] = pb;
    }
    const int NW1_4 = RR * HH1 * FIN1 / 4;
    for (int i4 = i0; i4 < NW1_4; i4 += stride) {
        int i = i4 * 4;
        int k = i % FIN1; int rh = i / FIN1; int hh = rh % HH1; int r = rh / HH1;
        const float* s = &W1[((size_t)r * FIN1 + k) * HH1 + hh];
        uint2 pk;
        pk.x = (unsigned)f2bf(s[0]) | ((unsigned)f2bf(s[HH1]) << 16);
        pk.y = (unsigned)f2bf(s[2 * HH1]) | ((unsigned)f2bf(s[3 * HH1]) << 16);
        ((uint2*)w1t)[i4] = pk;
    }
    const int NW2_4 = RR * HH2 * HH1 / 4;
    for (int i4 = i0; i4 < NW2_4; i4 += stride) {
        int i = i4 * 4;
        int k = i % HH1; int rh = i / HH1; int hh = rh % HH2; int r = rh / HH2;
        const float* s = &W2[((size_t)r * HH1 + k) * HH2 + hh];
        uint2 pk;
        pk.x = (unsigned)f2bf(s[0]) | ((unsigned)f2bf(s[HH2]) << 16);
        pk.y = (unsigned)f2bf(s[2 * HH2]) | ((unsigned)f2bf(s[3 * HH2]) << 16);
        ((uint2*)w2t)[i4] = pk;
    }
    const int NR1_4 = HH1 * FIN1 / 4;
    for (int i4 = i0; i4 < NR1_4; i4 += stride) {
        int i = i4 * 4;
        int k = i % FIN1; int hh = i / FIN1;
        const float* s = &root1[(size_t)k * HH1 + hh];
        uint2 pk;
        pk.x = (unsigned)f2bf(s[0]) | ((unsigned)f2bf(s[HH1]) << 16);
        pk.y = (unsigned)f2bf(s[2 * HH1]) | ((unsigned)f2bf(s[3 * HH1]) << 16);
        ((uint2*)r1t)[i4] = pk;
    }
    const int NR2_4 = HH2 * HH1 / 4;
    for (int i4 = i0; i4 < NR2_4; i4 += stride) {
        int i = i4 * 4;
        int k = i % HH1; int hh = i / HH1;
        const float* s = &root2[(size_t)k * HH2 + hh];
        uint2 pk;
        pk.x = (unsigned)f2bf(s[0]) | ((unsigned)f2bf(s[HH2]) << 16);
        pk.y = (unsigned)f2bf(s[2 * HH2]) | ((unsigned)f2bf(s[3 * HH2]) << 16);
        ((uint2*)r2t)[i4] = pk;
    }
    const int NCW_4 = CLS_N * CLS_K / 4;
    for (int i4 = i0; i4 < NCW_4; i4 += stride) {
        int i = i4 * 4;
        int k = i % CLS_K; int n = i / CLS_K;
        uint2 pk = {0u, 0u};
        if (n < RR && k < 448) {
            const float* s = &clsW[(size_t)k * RR + n];
            pk.x = (unsigned)f2bf(s[0]) | ((unsigned)f2bf(s[RR]) << 16);
            pk.y = (unsigned)f2bf(s[2 * RR]) | ((unsigned)f2bf(s[3 * RR]) << 16);
        }
        ((uint2*)cwt)[i4] = pk;
    }
}

// exclusive scan of per-dst degrees -> dstOff[NN+1] (single block)
__global__ void k_scanD(const int* __restrict__ cntD, int* __restrict__ dstOff) {
    __shared__ int s[256];
    int t = threadIdx.x;
    constexpr int PER = (NN + 255) / 256;
    int lo = t * PER, hi = min(NN, lo + PER);
    int sum = 0;
    for (int i = lo; i < hi; i++) sum += cntD[i];
    s[t] = sum;
    __syncthreads();
    for (int ofs = 1; ofs < 256; ofs <<= 1) {
        int v = 0;
        if (t >= ofs) v = s[t - ofs];
        __syncthreads();
        if (t >= ofs) s[t] += v;
        __syncthreads();
    }
    int run = s[t] - sum;
    for (int i = lo; i < hi; i++) { dstOff[i] = run; run += cntD[i]; }
    if (t == 255) dstOff[NN] = run;
}

// posD (sequential write) + rdP + dstP (pos -> dst, for fused reduction)
__global__ void k_post(const int* __restrict__ ei, const int* __restrict__ et0,
                       const int* __restrict__ et1, const int* __restrict__ dstOff,
                       const int* __restrict__ slotE,
                       int* __restrict__ posD, unsigned int* __restrict__ rdP,
                       int* __restrict__ dstP) {
    int e = blockIdx.x * 256 + threadIdx.x;
    if (e < EE) {
        int d = ei[EE + e];
        int pos = dstOff[d] + slotE[e];
        posD[e] = pos;
        rdP[pos] = (unsigned)et0[e] | ((unsigned)et1[e] << 16);
        dstP[pos] = d;
    }
}

// phase 1: per-bucket exclusive prefix over the 256 histogram blocks.
__global__ void k_scanB1(const int* __restrict__ bh0, const int* __restrict__ bh1,
                         int* __restrict__ bb0, int* __restrict__ bb1,
                         int* __restrict__ hT) {
    int w = (blockIdx.x * 256 + threadIdx.x) >> 6;
    int lane = threadIdx.x & 63;
    if (w >= 2 * NB2) return;
    int s = w / NB2, k = w % NB2;
    const int* bh = s ? bh1 : bh0;
    int* bb = s ? bb1 : bb0;
    int v[4];
    #pragma unroll
    for (int i = 0; i < 4; i++) v[i] = bh[(size_t)(lane * 4 + i) * NB2 + k];
    int ls = v[0] + v[1] + v[2] + v[3];
    int inc = ls;
    #pragma unroll
    for (int ofs = 1; ofs < 64; ofs <<= 1) {
        int o = __shfl_up(inc, ofs);
        if (lane >= ofs) inc += o;
    }
    int run = inc - ls;   // exclusive base for this lane
    #pragma unroll
    for (int i = 0; i < 4; i++) {
        bb[(size_t)(lane * 4 + i) * NB2 + k] = run;
        run += v[i];
    }
    if (lane == 63) hT[s * NB2 + k] = run;  // column total
}

// phase 2 (single block): bucket offsets + tile tables from the 1040 totals.
__global__ void k_scanB2(const int* __restrict__ hT,
                         int* offB0, int* offB1,
                         int* tilB0, int* tilT0, int* tilB1, int* tilT1) {
    __shared__ int h[2][NB2];
    __shared__ int o[2][NB2 + 1];
    __shared__ int to[2][NB2 + 1];
    __shared__ int csumE[2][8], csumT[2][8];
    int t = threadIdx.x;
    for (int p = t; p < 2 * NB2; p += 256) h[p / NB2][p % NB2] = hT[p];
    __syncthreads();
    if (t < 16) {
        int s = t / 8, c = t % 8;
        int runE = 0, runT = 0;
        for (int k = c * RR; k < (c + 1) * RR; k++) {
            o[s][k] = runE;  runE += h[s][k];
            to[s][k] = runT; runT += (h[s][k] + BM - 1) / BM;
        }
        csumE[s][c] = runE; csumT[s][c] = runT;
    }
    __syncthreads();
    if (t < 2) {
        int runE = 0, runT = 0;
        for (int c = 0; c < 8; c++) {
            int e = csumE[t][c], tt = csumT[t][c];
            csumE[t][c] = runE; csumT[t][c] = runT;
            runE += e; runT += tt;
        }
        o[t][NB2] = runE; to[t][NB2] = runT;
    }
    __syncthreads();
    if (t < 16) {
        int s = t / 8, c = t % 8;
        for (int k = c * RR; k < (c + 1) * RR; k++) {
            o[s][k] += csumE[s][c];
            to[s][k] += csumT[s][c];
        }
    }
    __syncthreads();
    for (int p = t; p <= NB2; p += 256) { offB0[p] = o[0][p]; offB1[p] = o[1][p]; }
    for (int i = t; i < MAXT2; i += 256) {
        #pragma unroll
        for (int s = 0; s < 2; s++) {
            int total = to[s][NB2];
            int bkt = -1, ti = 0;
            if (i < total) {
                int lo = 0, hi = NB2;
                while (hi - lo > 1) { int mid = (lo + hi) >> 1; if (to[s][mid] <= i) lo = mid; else hi = mid; }
                bkt = lo;
                ti = i - to[s][lo];
            }
            if (s == 0) { tilB0[i] = bkt; tilT0[i] = ti; }
            else        { tilB1[i] = bkt; tilT1[i] = ti; }
        }
    }
}

// bucket-sorted perm placement with deterministic bases.
__global__ void k_fillB(const int* __restrict__ ei, const int* __restrict__ et0,
                        const int* __restrict__ et1, const int* __restrict__ posD,
                        const int* __restrict__ offB0, const int* __restrict__ offB1,
                        const int* __restrict__ bb0, const int* __restrict__ bb1,
                        unsigned int* perm0, unsigned int* perm1) {
    __shared__ int lc[2][NB2];
    __shared__ int lb[2][NB2];
    int t = threadIdx.x;
    for (int p = t; p < NB2; p += 256) {
        lc[0][p] = 0; lc[1][p] = 0;
        lb[0][p] = offB0[p] + bb0[blockIdx.x * NB2 + p];
        lb[1][p] = offB1[p] + bb1[blockIdx.x * NB2 + p];
    }
    __syncthreads();
    int base = blockIdx.x * EPB;
    for (int i = t; i < EPB; i += 256) {
        int e = base + i;
        int src = ei[e];                 // sequential read
        int pos = posD[e];               // sequential read
        int oct = src / NPO;
        unsigned int packed = ((unsigned)(src - oct * NPO) << 20) | (unsigned)pos;
        int k0 = oct * RR + et0[e];
        int k1 = oct * RR + et1[e];
        int p0 = atomicAdd(&lc[0][k0], 1);
        int p1 = atomicAdd(&lc[1][k1], 1);
        perm0[lb[0][k0] + p0] = packed;
        perm1[lb[1][k1] + p1] = packed;
    }
}

// per-(relation,dst) mean weights inside each dst segment -> pos-space arrays
__global__ void k_wts(const int* __restrict__ dstOff, const unsigned int* __restrict__ rdP,
                      float* __restrict__ wD0, float* __restrict__ wD1) {
    constexpr int CAP = 96;
    __shared__ unsigned int ld[4][CAP];
    int wave = threadIdx.x >> 6;
    int lane = threadIdx.x & 63;
    int d = blockIdx.x * 4 + wave;
    int j0 = 0, deg = 0;
    if (d < NN) { j0 = dstOff[d]; deg = dstOff[d + 1] - j0; }
    for (int j = lane; j < deg && j < CAP; j += 64) ld[wave][j] = rdP[j0 + j];
    __syncthreads();
    for (int j = lane; j < deg; j += 64) {
        unsigned int my = (j < CAP) ? ld[wave][j] : rdP[j0 + j];
        unsigned int m0 = my & 0xffffu, m1 = my >> 16;
        int c0 = 0, c1 = 0;
        for (int k = 0; k < deg; k++) {
            unsigned int p = (k < CAP) ? ld[wave][k] : rdP[j0 + k];
            c0 += ((p & 0xffffu) == m0);
            c1 += ((p >> 16) == m1);
        }
        wD0[j0 + j] = 1.0f / (float)c0;
        wD1[j0 + j] = 1.0f / (float)c1;
    }
}

// root-term GEMM via MFMA: O[n,h] = Xb[n,:] @ rootT[h,:] + bias[h]  (fp32 out)
template <int FIN, int HOUT>
__launch_bounds__(256, 3)
__global__ void k_bgemm(const unsigned short* __restrict__ X0,
                        const unsigned short* __restrict__ X1,
                        const unsigned short* __restrict__ X2,
                        const unsigned short* __restrict__ rootT,
                        const float* __restrict__ bias,
                        float* O0, float* O1, float* O2) {
    const int enc = blockIdx.y;
    const unsigned short* X = enc == 0 ? X0 : enc == 1 ? X1 : X2;
    float* O = enc == 0 ? O0 : enc == 1 ? O1 : O2;
    int n0 = blockIdx.x * BM;
    int mcount = min(BM, NN - n0);

    constexpr int LDK = FIN + 8;
    __shared__ unsigned short As[BM][LDK];
    __shared__ unsigned short Bs[HOUT][LDK];

    int tid = threadIdx.x;
    {
        constexpr int CHB = HOUT * FIN / 8;
        for (int c = tid; c < CHB; c += 256) {
            int row = c / (FIN / 8), cc = c % (FIN / 8);
            *(uint4*)&Bs[row][cc * 8] = *(const uint4*)&rootT[row * FIN + cc * 8];
        }
    }
    {
        constexpr int CHA = BM * FIN / 8;
        for (int c = tid; c < CHA; c += 256) {
            int row = c / (FIN / 8), cc = c % (FIN / 8);
            uint4 v = {0u, 0u, 0u, 0u};
            if (row < mcount) v = *(const uint4*)&X[(size_t)(n0 + row) * FIN + cc * 8];
            *(uint4*)&As[row][cc * 8] = v;
        }
    }
    __syncthreads();

    const int wave = tid >> 6;
    const int lane = tid & 63;
    const int q = lane >> 4;
    const int ln = lane & 15;
    constexpr int NT = HOUT / 16;
    constexpr int KS = FIN / 32;
    const int mbase = wave * 32;

    floatx4 acc[2][NT];
    #pragma unroll
    for (int a = 0; a < 2; a++)
        #pragma unroll
        for (int nt = 0; nt < NT; nt++) acc[a][nt] = floatx4{0.f, 0.f, 0.f, 0.f};

    for (int ks = 0; ks < KS; ks++) {
        int kk = ks * 32 + q * 8;
        short8 af0 = *(const short8*)&As[mbase + ln][kk];
        short8 af1 = *(const short8*)&As[mbase + 16 + ln][kk];
        #pragma unroll
        for (int nt = 0; nt < NT; nt++) {
            short8 bf = *(const short8*)&Bs[nt * 16 + ln][kk];
            acc[0][nt] = __builtin_amdgcn_mfma_f32_16x16x32_bf16(af0, bf, acc[0][nt], 0, 0, 0);
            acc[1][nt] = __builtin_amdgcn_mfma_f32_16x16x32_bf16(af1, bf, acc[1][nt], 0, 0, 0);
        }
    }

    #pragma unroll
    for (int mt = 0; mt < 2; mt++) {
        #pragma unroll
        for (int rr2 = 0; rr2 < 4; rr2++) {
            int i = mbase + mt * 16 + q * 4 + rr2;
            int n = n0 + i;
            if (i < mcount) {
                #pragma unroll
                for (int nt = 0; nt < NT; nt++)
                    O[(size_t)n * HOUT + nt * 16 + ln] = acc[mt][nt][rr2] + bias[nt * 16 + ln];
            }
        }
    }
}

// bucket-grouped gather-GEMM with MFMA, staged through LDS (R4 core — the
// proven fastest structure), with the REDUCTION FUSED into the epilogue:
// instead of writing bf16 msg rows to HBM (160 MB/dispatch) and re-reading
// them in k_reduce, each output element is scaled by the per-(rel,dst) mean
// weight and atomically accumulated into a fixed-point (i32, 2^20) per-enc
// accumulator. Integer atomics are order-independent -> results stay
// deterministic across replays; quantization (~3e-5) is far below the bf16
// msg rounding it replaces. The 23 MB accumulator set lives in L2/L3.
template <int FIN, int HOUT>
__launch_bounds__(512, 6)
__global__ void k_gemm(GemmArgs ga, const unsigned short* __restrict__ WT,
                       const int* __restrict__ dstP) {
    const GemmEnc ge = ga.e[blockIdx.y];
    int b = blockIdx.x;
    int bkt = ge.tilB[b];
    if (bkt < 0) return;
    int r = bkt % RR;
    int srcBase = (bkt / RR) * NPO;
    int t = ge.tilT[b];
    int ebase = ge.offB[bkt] + t * BM;
    int mcount = min(BM, ge.offB[bkt + 1] - ebase);

    constexpr int LDK = FIN + 8;
    __shared__ unsigned short As[BM][LDK];
    __shared__ unsigned short Bs[HOUT][LDK];
    __shared__ int Sr[BM];
    __shared__ int Dd[BM];
    __shared__ float Wt[BM];

    int tid = threadIdx.x;
    if (tid < BM) {
        if (tid < mcount) {
            unsigned int p = ge.perm[ebase + tid];   // sequential
            int pos = (int)(p & 0xFFFFFu);
            Sr[tid] = srcBase + (int)(p >> 20);
            Dd[tid] = dstP[pos];
            Wt[tid] = ge.wD[pos];
        } else { Sr[tid] = -1; Dd[tid] = 0; Wt[tid] = 0.f; }
    }
    __syncthreads();

    {
        const unsigned short* Wr = WT + (size_t)r * HOUT * FIN;
        constexpr int CHB = HOUT * FIN / 8;
        for (int c = tid; c < CHB; c += 512) {
            int row = c / (FIN / 8), cc = c % (FIN / 8);
            *(uint4*)&Bs[row][cc * 8] = *(const uint4*)&Wr[row * FIN + cc * 8];
        }
    }
    {
        constexpr int CHA = BM * FIN / 8;
        for (int c = tid; c < CHA; c += 512) {
            int row = c / (FIN / 8), cc = c % (FIN / 8);
            int s = Sr[row];
            uint4 v = {0u, 0u, 0u, 0u};
            if (s >= 0) v = *(const uint4*)&ge.X[(size_t)s * FIN + cc * 8];
            *(uint4*)&As[row][cc * 8] = v;
        }
    }
    __syncthreads();

    const int wave = tid >> 6;       // 0..7
    const int lane = tid & 63;
    const int q = lane >> 4;
    const int ln = lane & 15;
    constexpr int NT = HOUT / 16;
    constexpr int KS = FIN / 32;
    const int mbase = wave * 16;     // one 16-row M-tile per wave

    floatx4 acc[NT];
    #pragma unroll
    for (int nt = 0; nt < NT; nt++) acc[nt] = floatx4{0.f, 0.f, 0.f, 0.f};

    #pragma unroll
    for (int ks = 0; ks < KS; ks++) {
        int kk = ks * 32 + q * 8;
        short8 af = *(const short8*)&As[mbase + ln][kk];
        #pragma unroll
        for (int nt = 0; nt < NT; nt++) {
            short8 bf = *(const short8*)&Bs[nt * 16 + ln][kk];
            acc[nt] = __builtin_amdgcn_mfma_f32_16x16x32_bf16(af, bf, acc[nt], 0, 0, 0);
        }
    }

    // fused-reduce epilogue: weighted fixed-point atomic accumulate per dst
    #pragma unroll
    for (int rr2 = 0; rr2 < 4; rr2++) {
        int i = mbase + q * 4 + rr2;
        if (i < mcount) {
            float w = Wt[i];
            int* arow = ge.acc + (size_t)Dd[i] * HOUT + ln;
            #pragma unroll
            for (int nt = 0; nt < NT; nt++) {
                int fx = __float2int_rn(w * acc[nt][rr2] * FXS);
                atomicAdd(arow + nt * 16, fx);
            }
        }
    }
}

// finalize layer 1: h1 = relu(root_base + acc*2^-20); write f32 back + bf16
__global__ void k_fin1(float* __restrict__ h, const int* __restrict__ acc,
                       unsigned short* __restrict__ hb) {
    int i = blockIdx.x * 256 + threadIdx.x;
    const int N4 = 3 * NN * HH1 / 4;
    if (i < N4) {
        float4 b = ((const float4*)h)[i];
        int4 a = ((const int4*)acc)[i];
        float v0 = fmaxf(b.x + (float)a.x * FXSI, 0.f);
        float v1 = fmaxf(b.y + (float)a.y * FXSI, 0.f);
        float v2 = fmaxf(b.z + (float)a.z * FXSI, 0.f);
        float v3 = fmaxf(b.w + (float)a.w * FXSI, 0.f);
        ((float4*)h)[i] = float4{v0, v1, v2, v3};
        uint2 pk;
        pk.x = (unsigned)f2bf(v0) | ((unsigned)f2bf(v1) << 16);
        pk.y = (unsigned)f2bf(v2) | ((unsigned)f2bf(v3) << 16);
        ((uint2*)hb)[i] = pk;
    }
}

// finalize layer 2: x2 += acc*2^-20 (no relu)
__global__ void k_fin2(Fin2P fp, const int* __restrict__ acc) {
    int enc = blockIdx.y;
    float* o = fp.o[enc];
    const int* a = acc + (size_t)enc * NN * HH2;
    int i = blockIdx.x * 256 + threadIdx.x;
    const int N4 = NN * HH2 / 4;
    if (i < N4) {
        float4 b = ((const float4*)o)[i];
        int4 v = ((const int4*)a)[i];
        b.x += (float)v.x * FXSI;
        b.y += (float)v.y * FXSI;
        b.z += (float)v.z * FXSI;
        b.w += (float)v.w * FXSI;
        ((float4*)o)[i] = b;
    }
}

// column partial sums of x2_o -> part[block][32] (plain stores, deterministic)
__global__ void k_mean(const float* __restrict__ x2o, float* __restrict__ part) {
    __shared__ float s[256];
    int t = threadIdx.x; int hh = t & 31; int g = t >> 5;
    float acc = 0.f;
    for (int n = blockIdx.x * 8 + g; n < NN; n += gridDim.x * 8)
        acc += x2o[(size_t)n * 32 + hh];
    s[t] = acc;
    __syncthreads();
    if (t < 32) {
        float v = 0.f;
        for (int gg = 0; gg < 8; gg++) v += s[gg * 32 + t];
        part[blockIdx.x * 32 + t] = v;
    }
}

// deterministic final column sum: csum[c] = sum_b part[b][c] in fixed order
__global__ void k_csum(const float* __restrict__ part, float* __restrict__ csum) {
    int t = threadIdx.x;
    if (t < 32) {
        double a = 0.0;
        for (int b = 0; b < 256; b++) a += (double)part[b * 32 + t];
        csum[t] = (float)a;
    }
}

// c = sigmoid(csum/N); v = disc_W @ c; bilinear scores
__global__ void k_disc(const float* __restrict__ x2o, const float* __restrict__ x2a,
                       const float* __restrict__ x2aa, const float* __restrict__ csum,
                       const float* __restrict__ discW, const float* __restrict__ discb,
                       float* ret_os, float* ret_osa) {
    __shared__ float c[32], v[32];
    int t = threadIdx.x;
    if (t < 32) c[t] = 1.f / (1.f + expf(-csum[t] * (1.f / NN)));
    __syncthreads();
    if (t < 32) {
        float a = 0.f;
        for (int j = 0; j < 32; j++) a += discW[t * 32 + j] * c[j];
        v[t] = a;
    }
    __syncthreads();
    float db = discb[0];
    int n = blockIdx.x * 256 + t;
    if (n < NN) {
        float s1 = 0.f, s2 = 0.f, s3 = 0.f;
        for (int j = 0; j < 32; j++) {
            float vj = v[j];
            s1 += x2o[(size_t)n * 32 + j] * vj;
            s2 += x2a[(size_t)n * 32 + j] * vj;
            s3 += x2aa[(size_t)n * 32 + j] * vj;
        }
        ret_os[n * 2] = s1 + db;  ret_os[n * 2 + 1] = s2 + db;
        ret_osa[n * 2] = s1 + db; ret_osa[n * 2 + 1] = s3 + db;
    }
}

// pair classifier as MFMA GEMM (K padded to 512, N padded to 80)
__launch_bounds__(256, 2)
__global__ void k_clsg(const float* __restrict__ h1o, const float* __restrict__ x2o,
                       const float* __restrict__ feat, const float* __restrict__ attt,
                       const int* __restrict__ idx,
                       const unsigned short* __restrict__ cwt,
                       const float* __restrict__ clsb, float* __restrict__ log_out) {
    constexpr int LDK = CLS_CK + 8;
    __shared__ unsigned short As[CLS_BM][LDK];
    __shared__ unsigned short Bs[CLS_N][LDK];
    __shared__ int nd[2][CLS_BM];

    int tid = threadIdx.x;
    int p0 = blockIdx.x * CLS_BM;
    if (tid < CLS_BM) {
        nd[0][tid] = idx[p0 + tid];
        nd[1][tid] = idx[BB + p0 + tid];
    }
    float a0 = attt[0], a1 = attt[1];

    const int wave = tid >> 6;
    const int lane = tid & 63;
    const int q = lane >> 4;
    const int ln = lane & 15;
    constexpr int NT = CLS_N / 16;
    const int mbase = wave * 16;

    floatx4 acc[NT];
    #pragma unroll
    for (int nt = 0; nt < NT; nt++) acc[nt] = floatx4{0.f, 0.f, 0.f, 0.f};

    for (int ch = 0; ch < CLS_K / CLS_CK; ch++) {
        int kbase = ch * CLS_CK;
        __syncthreads();
        for (int c = tid; c < CLS_N * CLS_CK / 8; c += 256) {
            int row = c / (CLS_CK / 8), cc = c % (CLS_CK / 8);
            *(uint4*)&Bs[row][cc * 8] = *(const uint4*)&cwt[(size_t)row * CLS_K + kbase + cc * 8];
        }
        for (int c = tid; c < CLS_BM * CLS_CK / 4; c += 256) {
            int row = c / (CLS_CK / 4);
            int j4 = (c % (CLS_CK / 4)) * 4;
            int j = kbase + j4;
            float4 v = {0.f, 0.f, 0.f, 0.f};
            if (j < 448) {
                int hseg = j / 224, jj = j % 224;
                int node = nd[hseg][row];
                if (jj < 64) {
                    v = *(const float4*)&h1o[(size_t)node * 64 + jj];
                    v.x *= a0; v.y *= a0; v.z *= a0; v.w *= a0;
                } else if (jj < 96) {
                    v = *(const float4*)&x2o[(size_t)node * 32 + (jj - 64)];
                    v.x *= a1; v.y *= a1; v.z *= a1; v.w *= a1;
                } else {
                    v = *(const float4*)&feat[(size_t)node * 128 + (jj - 96)];
                }
            }
            uint2 pk;
            pk.x = (unsigned)f2bf(v.x) | ((unsigned)f2bf(v.y) << 16);
            pk.y = (unsigned)f2bf(v.z) | ((unsigned)f2bf(v.w) << 16);
            *(uint2*)&As[row][j4] = pk;
        }
        __syncthreads();
        #pragma unroll
        for (int ks = 0; ks < CLS_CK / 32; ks++) {
            int kk = ks * 32 + q * 8;
            short8 af = *(const short8*)&As[mbase + ln][kk];
            #pragma unroll
            for (int nt = 0; nt < NT; nt++) {
                short8 bf = *(const short8*)&Bs[nt * 16 + ln][kk];
                acc[nt] = __builtin_amdgcn_mfma_f32_16x16x32_bf16(af, bf, acc[nt], 0, 0, 0);
            }
        }
    }

    #pragma unroll
    for (int rr2 = 0; rr2 < 4; rr2++) {
        int i = mbase + q * 4 + rr2;
        int pair = p0 + i;
        #pragma unroll
        for (int nt = 0; nt < NT; nt++) {
            int col = nt * 16 + ln;
            if (col < RR)
                log_out[(size_t)pair * RR + col] = acc[nt][rr2] + clsb[col];
        }
    }
}

extern "C" void kernel_launch(void* const* d_in, const int* in_sizes, int n_in,
                              void* d_out, int out_size, void* d_ws, size_t ws_size,
                              hipStream_t stream) {
    const float* x_o   = (const float*)d_in[0];
    const float* x_a   = (const float*)d_in[1];
    const float* feat  = (const float*)d_in[2];
    const float* W1    = (const float*)d_in[3];
    const float* root1 = (const float*)d_in[4];
    const float* b1    = (const float*)d_in[5];
    const float* W2    = (const float*)d_in[6];
    const float* root2 = (const float*)d_in[7];
    const float* b2    = (const float*)d_in[8];
    const float* attt  = (const float*)d_in[9];
    const float* discW = (const float*)d_in[10];
    const float* discb = (const float*)d_in[11];
    const float* clsW  = (const float*)d_in[12];
    const float* clsb  = (const float*)d_in[13];
    const int* ei      = (const int*)d_in[14];
    const int* et0     = (const int*)d_in[15];
    const int* et1     = (const int*)d_in[16];
    const int* idx     = (const int*)d_in[17];

    char* ws = (char*)d_ws;
    float* csum = (float*)(ws + OFF_CSUM);
    int* cntD  = (int*)(ws + OFF_CNTD);
    int* dstOff = (int*)(ws + OFF_DSTOFF);
    int* bh0   = (int*)(ws + OFF_BH0);
    int* bh1   = (int*)(ws + OFF_BH1);
    int* bb0   = (int*)(ws + OFF_BB0);
    int* bb1   = (int*)(ws + OFF_BB1);
    int* hT    = (int*)(ws + OFF_HT);
    int* offB0 = (int*)(ws + OFF_OFFB0);
    int* offB1 = (int*)(ws + OFF_OFFB1);
    int* tilB0 = (int*)(ws + OFF_TILB0);
    int* tilT0 = (int*)(ws + OFF_TILT0);
    int* tilB1 = (int*)(ws + OFF_TILB1);
    int* tilT1 = (int*)(ws + OFF_TILT1);
    int* slotE = (int*)(ws + OFF_SLOT);
    int* posD  = (int*)(ws + OFF_POSD);
    unsigned int* rdP = (unsigned int*)(ws + OFF_RDP);
    float* wD0 = (float*)(ws + OFF_WD0);
    float* wD1 = (float*)(ws + OFF_WD1);
    unsigned int* perm0 = (unsigned int*)(ws + OFF_PERM0);
    unsigned int* perm1 = (unsigned int*)(ws + OFF_PERM1);
    unsigned short* xob = (unsigned short*)(ws + OFF_XOB);
    unsigned short* xab = (unsigned short*)(ws + OFF_XAB);
    float* h1o  = (float*)(ws + OFF_H1);
    float* h1a  = h1o + (size_t)NN * HH1;
    float* h1aa = h1a + (size_t)NN * HH1;
    unsigned short* h1bo  = (unsigned short*)(ws + OFF_H1B);
    unsigned short* h1ba  = h1bo + (size_t)NN * HH1;
    unsigned short* h1baa = h1ba + (size_t)NN * HH1;
    float* x2a  = (float*)(ws + OFF_X2A);
    float* x2aa = (float*)(ws + OFF_X2AA);
    unsigned short* w1t = (unsigned short*)(ws + OFF_W1BT);
    unsigned short* w2t = (unsigned short*)(ws + OFF_W2BT);
    unsigned short* r1t = (unsigned short*)(ws + OFF_R1T);
    unsigned short* r2t = (unsigned short*)(ws + OFF_R2T);
    unsigned short* cwt = (unsigned short*)(ws + OFF_CWT);
    float* part = (float*)(ws + OFF_PART);
    int* acc1  = (int*)(ws + OFF_ACC1);
    int* acc2  = (int*)(ws + OFF_ACC2);
    int* dstP  = (int*)(ws + OFF_DSTP);

    float* out = (float*)d_out;
    float* log_out = out + O_LOG;
    float* ret_os  = out + O_ROS;
    float* ret_osa = out + O_ROSA;
    float* x2o     = out + O_X2O;

    // 1) zero control block (~80 KB) + fixed-point accumulators (23 MB)
    hipMemsetAsync(ws, 0, ZERO_BYTES, stream);
    hipMemsetAsync(ws + OFF_ACC1, 0, ACC_ZB, stream);

    // 2) preprocessing: (octile,relation) bucket sort with packed metadata
    k_hist<<<GRID_PRE, 256, 0, stream>>>(ei, et0, et1, cntD, slotE, bh0, bh1,
                                         x_o, x_a, W1, W2, root1, root2, clsW,
                                         xob, xab, w1t, w2t, r1t, r2t, cwt);
    k_scanD<<<1, 256, 0, stream>>>(cntD, dstOff);
    k_post<<<2500, 256, 0, stream>>>(ei, et0, et1, dstOff, slotE, posD, rdP, dstP);
    k_scanB1<<<(2 * NB2 + 3) / 4, 256, 0, stream>>>(bh0, bh1, bb0, bb1, hT);
    k_scanB2<<<1, 256, 0, stream>>>(hT, offB0, offB1,
                                    tilB0, tilT0, tilB1, tilT1);
    k_fillB<<<NBH, 256, 0, stream>>>(ei, et0, et1, posD, offB0, offB1, bb0, bb1,
                                     perm0, perm1);
    k_wts<<<NN / 4, 256, 0, stream>>>(dstOff, rdP, wD0, wD1);

    // 3) layer 1: root GEMM writes base; fused gemm+reduce; finalize relu/bf16
    {
        dim3 gb(NBT, 3);
        k_bgemm<FIN1, HH1><<<gb, 256, 0, stream>>>(xob, xab, xob, r1t, b1,
                                                   h1o, h1a, h1aa);
        const unsigned short* Xs[3] = {xob, xab, xob};
        GemmArgs ga{};
        for (int enc = 0; enc < 3; enc++) {
            ga.e[enc].X    = Xs[enc];
            ga.e[enc].acc  = acc1 + (size_t)enc * NN * HH1;
            ga.e[enc].perm = enc == 2 ? perm1 : perm0;
            ga.e[enc].offB = enc == 2 ? offB1 : offB0;
            ga.e[enc].tilB = enc == 2 ? tilB1 : tilB0;
            ga.e[enc].tilT = enc == 2 ? tilT1 : tilT0;
            ga.e[enc].wD   = enc == 2 ? wD1 : wD0;
        }
        k_gemm<FIN1, HH1><<<dim3(MAXT2, 3), 512, 0, stream>>>(ga, w1t, dstP);
        k_fin1<<<(3 * NN * HH1 / 4 + 255) / 256, 256, 0, stream>>>(h1o, acc1, h1bo);
    }

    // 4) layer 2: root GEMM writes base; fused gemm+reduce; finalize add
    {
        dim3 gb(NBT, 3);
        k_bgemm<HH1, HH2><<<gb, 256, 0, stream>>>(h1bo, h1ba, h1baa, r2t, b2,
                                                  x2o, x2a, x2aa);
        const unsigned short* Xs[3] = {h1bo, h1ba, h1baa};
        GemmArgs ga{};
        for (int enc = 0; enc < 3; enc++) {
            ga.e[enc].X    = Xs[enc];
            ga.e[enc].acc  = acc2 + (size_t)enc * NN * HH2;
            ga.e[enc].perm = enc == 2 ? perm1 : perm0;
            ga.e[enc].offB = enc == 2 ? offB1 : offB0;
            ga.e[enc].tilB = enc == 2 ? tilB1 : tilB0;
            ga.e[enc].tilT = enc == 2 ? tilT1 : tilT0;
            ga.e[enc].wD   = enc == 2 ? wD1 : wD0;
        }
        k_gemm<HH1, HH2><<<dim3(MAXT2, 3), 512, 0, stream>>>(ga, w2t, dstP);
        Fin2P fp;
        fp.o[0] = x2o; fp.o[1] = x2a; fp.o[2] = x2aa;
        k_fin2<<<dim3(NN * HH2 / 4 / 256 + 1, 3), 256, 0, stream>>>(fp, acc2);
    }

    // 5) readout + discriminator + classifier
    k_mean<<<256, 256, 0, stream>>>(x2o, part);
    k_csum<<<1, 64, 0, stream>>>(part, csum);
    k_disc<<<(NN + 255) / 256, 256, 0, stream>>>(x2o, x2a, x2aa, csum, discW, discb,
                                                 ret_os, ret_osa);
    k_clsg<<<BB / CLS_BM, 256, 0, stream>>>(h1o, x2o, feat, attt, idx, cwt, clsb, log_out);
}

// Round 7
// 569.164 us; speedup vs baseline: 1.4722x; 1.4722x over previous
//
#include <hip/hip_runtime.h>
#include <hip/hip_bf16.h>

// ---------------- problem constants ----------------
#define NN 20000      // nodes
#define EE 640000     // edges
#define RR 65         // relations
#define FIN1 128      // input feat
#define HH1 64        // hidden1
#define HH2 32        // hidden2
#define BB 8192       // pairs

constexpr int BM = 128;                 // edge-tile rows per GEMM block
constexpr int NBH = 256;                // histogram/placement blocks
constexpr int GRID_PRE = 2048;          // k_hist launch grid (occupancy for conversions)
constexpr int EPB = EE / NBH;           // 2500 edges per block
constexpr int NBT = (NN + BM - 1) / BM; // 157 node tiles
constexpr int NOCT = 8;                 // src octiles (nodes per octile = 2500)
constexpr int NPO = NN / NOCT;          // 2500
constexpr int NB2 = NOCT * RR;          // 520 sort buckets (octile-major, relation inner)
constexpr int MAXT2 = EE / BM + NB2;    // 5520 tile upper bound

// classifier GEMM geometry (E[8192x448] @ clsW[448x65], padded)
constexpr int CLS_K  = 512;
constexpr int CLS_N  = 80;
constexpr int CLS_CK = 128;
constexpr int CLS_BM = 64;

typedef __attribute__((ext_vector_type(8))) short short8;   // 8 bf16 MFMA frag
typedef __attribute__((ext_vector_type(4))) float floatx4;  // 4 fp32 acc
typedef __attribute__((ext_vector_type(4))) unsigned int uint4e;  // 16B vector
typedef __attribute__((ext_vector_type(2))) unsigned int uint2e;  // 8B vector

// ---------------- workspace layout (bytes) ----------------
constexpr size_t aln(size_t x) { return (x + 255) & ~(size_t)255; }

constexpr size_t OFF_CSUM  = 0;                        // 32 f
constexpr size_t OFF_CNTD  = aln(OFF_CSUM + 32 * 4);  // NN int (dst degree)
constexpr size_t ZERO_BYTES = OFF_CNTD + (size_t)NN * 4;   // memset [0, ZERO_BYTES)
constexpr size_t OFF_DSTOFF = aln(ZERO_BYTES);         // NN+1 int
constexpr size_t OFF_BH0   = aln(OFF_DSTOFF + ((size_t)NN + 1) * 4); // NBH*NB2
constexpr size_t OFF_BH1   = OFF_BH0 + (size_t)NBH * NB2 * 4;
constexpr size_t OFF_BB0   = OFF_BH1 + (size_t)NBH * NB2 * 4;
constexpr size_t OFF_BB1   = OFF_BB0 + (size_t)NBH * NB2 * 4;
constexpr size_t OFF_HT    = aln(OFF_BB1 + (size_t)NBH * NB2 * 4);   // 2*NB2 int totals
constexpr size_t OFF_OFFB0 = aln(OFF_HT + (size_t)2 * NB2 * 4);      // NB2+1 int
constexpr size_t OFF_OFFB1 = OFF_OFFB0 + (NB2 + 1) * 4;
constexpr size_t OFF_TILB0 = aln(OFF_OFFB1 + (NB2 + 1) * 4);  // MAXT2 int
constexpr size_t OFF_TILT0 = OFF_TILB0 + (size_t)MAXT2 * 4;
constexpr size_t OFF_TILB1 = OFF_TILT0 + (size_t)MAXT2 * 4;
constexpr size_t OFF_TILT1 = OFF_TILB1 + (size_t)MAXT2 * 4;
constexpr size_t OFF_SLOT  = aln(OFF_TILT1 + (size_t)MAXT2 * 4);  // E int
constexpr size_t OFF_POSD  = OFF_SLOT + (size_t)EE * 4;           // E int (e -> dst pos)
constexpr size_t OFF_RDP   = OFF_POSD + (size_t)EE * 4;           // E uint (pos -> r0|r1<<16)
constexpr size_t OFF_WD0   = OFF_RDP + (size_t)EE * 4;            // E float (pos-space weights)
constexpr size_t OFF_WD1   = OFF_WD0 + (size_t)EE * 4;
constexpr size_t OFF_PERM0 = OFF_WD1 + (size_t)EE * 4;            // E uint (srcLocal<<20|pos)
constexpr size_t OFF_PERM1 = OFF_PERM0 + (size_t)EE * 4;
constexpr size_t OFF_XOB   = aln(OFF_PERM1 + (size_t)EE * 4);     // N*F bf16
constexpr size_t OFF_XAB   = OFF_XOB + (size_t)NN * FIN1 * 2;
constexpr size_t OFF_H1    = aln(OFF_XAB + (size_t)NN * FIN1 * 2); // 3 * N*64 f
constexpr size_t OFF_H1B   = OFF_H1 + (size_t)3 * NN * HH1 * 4;    // 3 * N*64 bf16
constexpr size_t OFF_X2A   = OFF_H1B + (size_t)3 * NN * HH1 * 2;   // N*32 f
constexpr size_t OFF_X2AA  = OFF_X2A + (size_t)NN * HH2 * 4;
constexpr size_t OFF_W1BT  = OFF_X2AA + (size_t)NN * HH2 * 4;      // R*64*128 bf16
constexpr size_t OFF_W2BT  = OFF_W1BT + (size_t)RR * HH1 * FIN1 * 2;
constexpr size_t OFF_R1T   = OFF_W2BT + (size_t)RR * HH2 * HH1 * 2;
constexpr size_t OFF_R2T   = OFF_R1T + (size_t)HH1 * FIN1 * 2;
constexpr size_t OFF_CWT   = OFF_R2T + (size_t)HH2 * HH1 * 2;
constexpr size_t OFF_PART  = aln(OFF_CWT + (size_t)CLS_N * CLS_K * 2); // 256*32 f partials
constexpr size_t OFF_MSG   = aln(OFF_PART + (size_t)256 * 32 * 4);     // msg buffers (1..3)
constexpr size_t MSG_B1    = (size_t)EE * HH1 * 2;   // one layer-1 msg buffer
constexpr size_t MSG_B2    = (size_t)EE * HH2 * 2;   // one layer-2 msg buffer
constexpr size_t WS_END    = OFF_MSG + MSG_B1;       // minimum required (1 buffer)

// output offsets (floats)
constexpr size_t O_LOG  = 0;
constexpr size_t O_ROS  = (size_t)BB * RR;
constexpr size_t O_ROSA = O_ROS + (size_t)NN * 2;
constexpr size_t O_X2O  = O_ROSA + (size_t)NN * 2;

__device__ inline unsigned short f2bf(float f) {
    __hip_bfloat16 h = __float2bfloat16(f);
    return *reinterpret_cast<unsigned short*>(&h);
}
__device__ inline float bfbits2f(unsigned int hi_bits) {
    return __uint_as_float(hi_bits);
}

// per-enc pointer bundles for merged launches
struct GemmEnc {
    const unsigned short* X;
    unsigned short* msg;
    const unsigned int* perm;
    const int* offB;
    const int* tilB;
    const int* tilT;
};
struct GemmArgs { GemmEnc e[3]; };

struct RedEnc {
    const unsigned short* msg;
    const float* wD;
    float* base;
    unsigned short* bfout;
};
struct RedArgs { RedEnc e[3]; };

// ---------------- preprocessing ----------------
// blocks < NBH: per-block 520-bin (octile,relation) histograms via LDS,
// per-dst degree + slot. ALL blocks: vectorized streaming bf16 conversions.
__global__ void k_hist(const int* __restrict__ ei, const int* __restrict__ et0,
                       const int* __restrict__ et1,
                       int* cntD, int* __restrict__ slotE,
                       int* __restrict__ bh0, int* __restrict__ bh1,
                       const float* __restrict__ x_o, const float* __restrict__ x_a,
                       const float* __restrict__ W1, const float* __restrict__ W2,
                       const float* __restrict__ root1, const float* __restrict__ root2,
                       const float* __restrict__ clsW,
                       unsigned short* xob, unsigned short* xab,
                       unsigned short* w1t, unsigned short* w2t,
                       unsigned short* r1t, unsigned short* r2t,
                       unsigned short* cwt) {
    __shared__ int lh0[NB2], lh1[NB2];
    int t = threadIdx.x;
    if (blockIdx.x < NBH) {
        for (int p = t; p < NB2; p += 256) { lh0[p] = 0; lh1[p] = 0; }
        __syncthreads();
        int base = blockIdx.x * EPB;
        for (int i = t; i < EPB; i += 256) {
            int e = base + i;
            int oct = ei[e] / NPO;
            atomicAdd(&lh0[oct * RR + et0[e]], 1);
            atomicAdd(&lh1[oct * RR + et1[e]], 1);
            slotE[e] = atomicAdd(&cntD[ei[EE + e]], 1);
        }
        __syncthreads();
        for (int p = t; p < NB2; p += 256) {
            bh0[blockIdx.x * NB2 + p] = lh0[p];
            bh1[blockIdx.x * NB2 + p] = lh1[p];
        }
    }
    // streaming conversions (grid-stride, vectorized 4-wide)
    int stride = gridDim.x * 256;
    int i0 = blockIdx.x * 256 + t;
    const int NX4 = NN * FIN1 / 4;
    const float4* xo4 = (const float4*)x_o;
    const float4* xa4 = (const float4*)x_a;
    for (int i = i0; i < NX4; i += stride) {
        float4 a = xo4[i], b = xa4[i];
        uint2 pa, pb;
        pa.x = (unsigned)f2bf(a.x) | ((unsigned)f2bf(a.y) << 16);
        pa.y = (unsigned)f2bf(a.z) | ((unsigned)f2bf(a.w) << 16);
        pb.x = (unsigned)f2bf(b.x) | ((unsigned)f2bf(b.y) << 16);
        pb.y = (unsigned)f2bf(b.z) | ((unsigned)f2bf(b.w) << 16);
        ((uint2*)xob)[i] = pa;
        ((uint2*)xab)[i] = pb;
    }
    const int NW1_4 = RR * HH1 * FIN1 / 4;
    for (int i4 = i0; i4 < NW1_4; i4 += stride) {
        int i = i4 * 4;
        int k = i % FIN1; int rh = i / FIN1; int hh = rh % HH1; int r = rh / HH1;
        const float* s = &W1[((size_t)r * FIN1 + k) * HH1 + hh];
        uint2 pk;
        pk.x = (unsigned)f2bf(s[0]) | ((unsigned)f2bf(s[HH1]) << 16);
        pk.y = (unsigned)f2bf(s[2 * HH1]) | ((unsigned)f2bf(s[3 * HH1]) << 16);
        ((uint2*)w1t)[i4] = pk;
    }
    const int NW2_4 = RR * HH2 * HH1 / 4;
    for (int i4 = i0; i4 < NW2_4; i4 += stride) {
        int i = i4 * 4;
        int k = i % HH1; int rh = i / HH1; int hh = rh % HH2; int r = rh / HH2;
        const float* s = &W2[((size_t)r * HH1 + k) * HH2 + hh];
        uint2 pk;
        pk.x = (unsigned)f2bf(s[0]) | ((unsigned)f2bf(s[HH2]) << 16);
        pk.y = (unsigned)f2bf(s[2 * HH2]) | ((unsigned)f2bf(s[3 * HH2]) << 16);
        ((uint2*)w2t)[i4] = pk;
    }
    const int NR1_4 = HH1 * FIN1 / 4;
    for (int i4 = i0; i4 < NR1_4; i4 += stride) {
        int i = i4 * 4;
        int k = i % FIN1; int hh = i / FIN1;
        const float* s = &root1[(size_t)k * HH1 + hh];
        uint2 pk;
        pk.x = (unsigned)f2bf(s[0]) | ((unsigned)f2bf(s[HH1]) << 16);
        pk.y = (unsigned)f2bf(s[2 * HH1]) | ((unsigned)f2bf(s[3 * HH1]) << 16);
        ((uint2*)r1t)[i4] = pk;
    }
    const int NR2_4 = HH2 * HH1 / 4;
    for (int i4 = i0; i4 < NR2_4; i4 += stride) {
        int i = i4 * 4;
        int k = i % HH1; int hh = i / HH1;
        const float* s = &root2[(size_t)k * HH2 + hh];
        uint2 pk;
        pk.x = (unsigned)f2bf(s[0]) | ((unsigned)f2bf(s[HH2]) << 16);
        pk.y = (unsigned)f2bf(s[2 * HH2]) | ((unsigned)f2bf(s[3 * HH2]) << 16);
        ((uint2*)r2t)[i4] = pk;
    }
    const int NCW_4 = CLS_N * CLS_K / 4;
    for (int i4 = i0; i4 < NCW_4; i4 += stride) {
        int i = i4 * 4;
        int k = i % CLS_K; int n = i / CLS_K;
        uint2 pk = {0u, 0u};
        if (n < RR && k < 448) {
            const float* s = &clsW[(size_t)k * RR + n];
            pk.x = (unsigned)f2bf(s[0]) | ((unsigned)f2bf(s[RR]) << 16);
            pk.y = (unsigned)f2bf(s[2 * RR]) | ((unsigned)f2bf(s[3 * RR]) << 16);
        }
        ((uint2*)cwt)[i4] = pk;
    }
}

// exclusive scan of per-dst degrees -> dstOff[NN+1] (single block)
__global__ void k_scanD(const int* __restrict__ cntD, int* __restrict__ dstOff) {
    __shared__ int s[256];
    int t = threadIdx.x;
    constexpr int PER = (NN + 255) / 256;
    int lo = t * PER, hi = min(NN, lo + PER);
    int sum = 0;
    for (int i = lo; i < hi; i++) sum += cntD[i];
    s[t] = sum;
    __syncthreads();
    for (int ofs = 1; ofs < 256; ofs <<= 1) {
        int v = 0;
        if (t >= ofs) v = s[t - ofs];
        __syncthreads();
        if (t >= ofs) s[t] += v;
        __syncthreads();
    }
    int run = s[t] - sum;
    for (int i = lo; i < hi; i++) { dstOff[i] = run; run += cntD[i]; }
    if (t == 255) dstOff[NN] = run;
}

// posD (sequential write) + rdP (the single scattered-write array)
__global__ void k_post(const int* __restrict__ ei, const int* __restrict__ et0,
                       const int* __restrict__ et1, const int* __restrict__ dstOff,
                       const int* __restrict__ slotE,
                       int* __restrict__ posD, unsigned int* __restrict__ rdP) {
    int e = blockIdx.x * 256 + threadIdx.x;
    if (e < EE) {
        int d = ei[EE + e];
        int pos = dstOff[d] + slotE[e];
        posD[e] = pos;
        rdP[pos] = (unsigned)et0[e] | ((unsigned)et1[e] << 16);
    }
}

// phase 1: per-bucket exclusive prefix over the 256 histogram blocks.
__global__ void k_scanB1(const int* __restrict__ bh0, const int* __restrict__ bh1,
                         int* __restrict__ bb0, int* __restrict__ bb1,
                         int* __restrict__ hT) {
    int w = (blockIdx.x * 256 + threadIdx.x) >> 6;
    int lane = threadIdx.x & 63;
    if (w >= 2 * NB2) return;
    int s = w / NB2, k = w % NB2;
    const int* bh = s ? bh1 : bh0;
    int* bb = s ? bb1 : bb0;
    int v[4];
    #pragma unroll
    for (int i = 0; i < 4; i++) v[i] = bh[(size_t)(lane * 4 + i) * NB2 + k];
    int ls = v[0] + v[1] + v[2] + v[3];
    int inc = ls;
    #pragma unroll
    for (int ofs = 1; ofs < 64; ofs <<= 1) {
        int o = __shfl_up(inc, ofs);
        if (lane >= ofs) inc += o;
    }
    int run = inc - ls;   // exclusive base for this lane
    #pragma unroll
    for (int i = 0; i < 4; i++) {
        bb[(size_t)(lane * 4 + i) * NB2 + k] = run;
        run += v[i];
    }
    if (lane == 63) hT[s * NB2 + k] = run;  // column total
}

// phase 2 (single block): bucket offsets + tile tables from the 1040 totals.
__global__ void k_scanB2(const int* __restrict__ hT,
                         int* offB0, int* offB1,
                         int* tilB0, int* tilT0, int* tilB1, int* tilT1) {
    __shared__ int h[2][NB2];
    __shared__ int o[2][NB2 + 1];
    __shared__ int to[2][NB2 + 1];
    __shared__ int csumE[2][8], csumT[2][8];
    int t = threadIdx.x;
    for (int p = t; p < 2 * NB2; p += 256) h[p / NB2][p % NB2] = hT[p];
    __syncthreads();
    if (t < 16) {
        int s = t / 8, c = t % 8;
        int runE = 0, runT = 0;
        for (int k = c * RR; k < (c + 1) * RR; k++) {
            o[s][k] = runE;  runE += h[s][k];
            to[s][k] = runT; runT += (h[s][k] + BM - 1) / BM;
        }
        csumE[s][c] = runE; csumT[s][c] = runT;
    }
    __syncthreads();
    if (t < 2) {
        int runE = 0, runT = 0;
        for (int c = 0; c < 8; c++) {
            int e = csumE[t][c], tt = csumT[t][c];
            csumE[t][c] = runE; csumT[t][c] = runT;
            runE += e; runT += tt;
        }
        o[t][NB2] = runE; to[t][NB2] = runT;
    }
    __syncthreads();
    if (t < 16) {
        int s = t / 8, c = t % 8;
        for (int k = c * RR; k < (c + 1) * RR; k++) {
            o[s][k] += csumE[s][c];
            to[s][k] += csumT[s][c];
        }
    }
    __syncthreads();
    for (int p = t; p <= NB2; p += 256) { offB0[p] = o[0][p]; offB1[p] = o[1][p]; }
    for (int i = t; i < MAXT2; i += 256) {
        #pragma unroll
        for (int s = 0; s < 2; s++) {
            int total = to[s][NB2];
            int bkt = -1, ti = 0;
            if (i < total) {
                int lo = 0, hi = NB2;
                while (hi - lo > 1) { int mid = (lo + hi) >> 1; if (to[s][mid] <= i) lo = mid; else hi = mid; }
                bkt = lo;
                ti = i - to[s][lo];
            }
            if (s == 0) { tilB0[i] = bkt; tilT0[i] = ti; }
            else        { tilB1[i] = bkt; tilT1[i] = ti; }
        }
    }
}

// bucket-sorted perm placement with deterministic bases.
__global__ void k_fillB(const int* __restrict__ ei, const int* __restrict__ et0,
                        const int* __restrict__ et1, const int* __restrict__ posD,
                        const int* __restrict__ offB0, const int* __restrict__ offB1,
                        const int* __restrict__ bb0, const int* __restrict__ bb1,
                        unsigned int* perm0, unsigned int* perm1) {
    __shared__ int lc[2][NB2];
    __shared__ int lb[2][NB2];
    int t = threadIdx.x;
    for (int p = t; p < NB2; p += 256) {
        lc[0][p] = 0; lc[1][p] = 0;
        lb[0][p] = offB0[p] + bb0[blockIdx.x * NB2 + p];
        lb[1][p] = offB1[p] + bb1[blockIdx.x * NB2 + p];
    }
    __syncthreads();
    int base = blockIdx.x * EPB;
    for (int i = t; i < EPB; i += 256) {
        int e = base + i;
        int src = ei[e];                 // sequential read
        int pos = posD[e];               // sequential read
        int oct = src / NPO;
        unsigned int packed = ((unsigned)(src - oct * NPO) << 20) | (unsigned)pos;
        int k0 = oct * RR + et0[e];
        int k1 = oct * RR + et1[e];
        int p0 = atomicAdd(&lc[0][k0], 1);
        int p1 = atomicAdd(&lc[1][k1], 1);
        perm0[lb[0][k0] + p0] = packed;
        perm1[lb[1][k1] + p1] = packed;
    }
}

// per-(relation,dst) mean weights inside each dst segment -> pos-space arrays
__global__ void k_wts(const int* __restrict__ dstOff, const unsigned int* __restrict__ rdP,
                      float* __restrict__ wD0, float* __restrict__ wD1) {
    constexpr int CAP = 96;
    __shared__ unsigned int ld[4][CAP];
    int wave = threadIdx.x >> 6;
    int lane = threadIdx.x & 63;
    int d = blockIdx.x * 4 + wave;
    int j0 = 0, deg = 0;
    if (d < NN) { j0 = dstOff[d]; deg = dstOff[d + 1] - j0; }
    for (int j = lane; j < deg && j < CAP; j += 64) ld[wave][j] = rdP[j0 + j];
    __syncthreads();
    for (int j = lane; j < deg; j += 64) {
        unsigned int my = (j < CAP) ? ld[wave][j] : rdP[j0 + j];
        unsigned int m0 = my & 0xffffu, m1 = my >> 16;
        int c0 = 0, c1 = 0;
        for (int k = 0; k < deg; k++) {
            unsigned int p = (k < CAP) ? ld[wave][k] : rdP[j0 + k];
            c0 += ((p & 0xffffu) == m0);
            c1 += ((p >> 16) == m1);
        }
        wD0[j0 + j] = 1.0f / (float)c0;
        wD1[j0 + j] = 1.0f / (float)c1;
    }
}

// root-term GEMM via MFMA: O[n,h] = Xb[n,:] @ rootT[h,:] + bias[h]  (fp32 out)
template <int FIN, int HOUT>
__launch_bounds__(256, 3)
__global__ void k_bgemm(const unsigned short* __restrict__ X0,
                        const unsigned short* __restrict__ X1,
                        const unsigned short* __restrict__ X2,
                        const unsigned short* __restrict__ rootT,
                        const float* __restrict__ bias,
                        float* O0, float* O1, float* O2) {
    const int enc = blockIdx.y;
    const unsigned short* X = enc == 0 ? X0 : enc == 1 ? X1 : X2;
    float* O = enc == 0 ? O0 : enc == 1 ? O1 : O2;
    int n0 = blockIdx.x * BM;
    int mcount = min(BM, NN - n0);

    constexpr int LDK = FIN + 8;
    __shared__ unsigned short As[BM][LDK];
    __shared__ unsigned short Bs[HOUT][LDK];

    int tid = threadIdx.x;
    {
        constexpr int CHB = HOUT * FIN / 8;
        for (int c = tid; c < CHB; c += 256) {
            int row = c / (FIN / 8), cc = c % (FIN / 8);
            *(uint4*)&Bs[row][cc * 8] = *(const uint4*)&rootT[row * FIN + cc * 8];
        }
    }
    {
        constexpr int CHA = BM * FIN / 8;
        for (int c = tid; c < CHA; c += 256) {
            int row = c / (FIN / 8), cc = c % (FIN / 8);
            uint4 v = {0u, 0u, 0u, 0u};
            if (row < mcount) v = *(const uint4*)&X[(size_t)(n0 + row) * FIN + cc * 8];
            *(uint4*)&As[row][cc * 8] = v;
        }
    }
    __syncthreads();

    const int wave = tid >> 6;
    const int lane = tid & 63;
    const int q = lane >> 4;
    const int ln = lane & 15;
    constexpr int NT = HOUT / 16;
    constexpr int KS = FIN / 32;
    const int mbase = wave * 32;

    floatx4 acc[2][NT];
    #pragma unroll
    for (int a = 0; a < 2; a++)
        #pragma unroll
        for (int nt = 0; nt < NT; nt++) acc[a][nt] = floatx4{0.f, 0.f, 0.f, 0.f};

    for (int ks = 0; ks < KS; ks++) {
        int kk = ks * 32 + q * 8;
        short8 af0 = *(const short8*)&As[mbase + ln][kk];
        short8 af1 = *(const short8*)&As[mbase + 16 + ln][kk];
        #pragma unroll
        for (int nt = 0; nt < NT; nt++) {
            short8 bf = *(const short8*)&Bs[nt * 16 + ln][kk];
            acc[0][nt] = __builtin_amdgcn_mfma_f32_16x16x32_bf16(af0, bf, acc[0][nt], 0, 0, 0);
            acc[1][nt] = __builtin_amdgcn_mfma_f32_16x16x32_bf16(af1, bf, acc[1][nt], 0, 0, 0);
        }
    }

    #pragma unroll
    for (int mt = 0; mt < 2; mt++) {
        #pragma unroll
        for (int rr2 = 0; rr2 < 4; rr2++) {
            int i = mbase + mt * 16 + q * 4 + rr2;
            int n = n0 + i;
            if (i < mcount) {
                #pragma unroll
                for (int nt = 0; nt < NT; nt++)
                    O[(size_t)n * HOUT + nt * 16 + ln] = acc[mt][nt][rr2] + bias[nt * 16 + ln];
            }
        }
    }
}

// bucket-grouped gather-GEMM with MFMA. R7 operand plan (reverse of failed
// R3): A fragments in REGISTERS (only KS short8 = 16 VGPR/lane; each lane's
// row-slice is KS independent 16 B loads, 4 q-lanes cover contiguous 64 B,
// X is L2-resident, each row still read once per block) + B staged in LDS
// (reused by all 8 waves; proven latency-decoupler). Dropping the 35 KB
// A-tile LDS: 53 -> ~19.4 KB, and launch_bounds(512,8) demands VGPR<=64 so
// 4 blocks x 8 waves = 32 waves/CU (100% occupancy, vs R4's 60%).
// Same ks-outer/nt-inner accumulation order -> bitwise-identical msg.
template <int FIN, int HOUT>
__launch_bounds__(512, 8)
__global__ void k_gemm(GemmArgs ga, const unsigned short* __restrict__ WT) {
    const GemmEnc ge = ga.e[blockIdx.y];
    int b = blockIdx.x;
    int bkt = ge.tilB[b];
    if (bkt < 0) return;
    int r = bkt % RR;
    int srcBase = (bkt / RR) * NPO;
    int t = ge.tilT[b];
    int ebase = ge.offB[bkt] + t * BM;
    int mcount = min(BM, ge.offB[bkt + 1] - ebase);

    constexpr int LDK = FIN + 8;
    constexpr int LDM = HOUT + 8;
    constexpr int BSZ = HOUT * LDK;      // Bs region (shorts)
    constexpr int MSZ = BM * LDM;        // epilogue msg staging (shorts)
    constexpr int USZ = BSZ > MSZ ? BSZ : MSZ;
    __shared__ unsigned short Us[USZ];   // Bs during K-loop, Ms in epilogue
    __shared__ int Sr[BM];
    __shared__ int Pd[BM];

    int tid = threadIdx.x;
    if (tid < BM) {
        if (tid < mcount) {
            unsigned int p = ge.perm[ebase + tid];   // sequential
            Sr[tid] = srcBase + (int)(p >> 20);
            Pd[tid] = (int)(p & 0xFFFFFu);
        } else { Sr[tid] = -1; Pd[tid] = 0; }
    }
    {
        const unsigned short* Wr = WT + (size_t)r * HOUT * FIN;
        constexpr int CHB = HOUT * FIN / 8;
        for (int c = tid; c < CHB; c += 512) {
            int row = c / (FIN / 8), cc = c % (FIN / 8);
            *(uint4*)&Us[row * LDK + cc * 8] = *(const uint4*)&Wr[row * FIN + cc * 8];
        }
    }
    __syncthreads();

    const int wave = tid >> 6;       // 0..7
    const int lane = tid & 63;
    const int q = lane >> 4;
    const int ln = lane & 15;
    constexpr int NT = HOUT / 16;
    constexpr int KS = FIN / 32;
    const int mbase = wave * 16;     // one 16-row M-tile per wave

    // A fragments -> registers: lane covers row Sr[mbase+ln], 16 B per ks
    int s = Sr[mbase + ln];
    short8 A[KS];
    #pragma unroll
    for (int ks = 0; ks < KS; ks++) A[ks] = short8{0,0,0,0,0,0,0,0};
    if (s >= 0) {
        const unsigned short* ap = ge.X + (size_t)s * FIN + q * 8;
        #pragma unroll
        for (int ks = 0; ks < KS; ks++) A[ks] = *(const short8*)(ap + ks * 32);
    }

    floatx4 acc[NT];
    #pragma unroll
    for (int nt = 0; nt < NT; nt++) acc[nt] = floatx4{0.f, 0.f, 0.f, 0.f};

    #pragma unroll
    for (int ks = 0; ks < KS; ks++) {
        int kk = ks * 32 + q * 8;
        #pragma unroll
        for (int nt = 0; nt < NT; nt++) {
            short8 bf = *(const short8*)&Us[(nt * 16 + ln) * LDK + kk];
            acc[nt] = __builtin_amdgcn_mfma_f32_16x16x32_bf16(A[ks], bf, acc[nt], 0, 0, 0);
        }
    }

    // epilogue: bf16 msgs through LDS (Us re-used), coalesced full-line scatter
    __syncthreads();   // everyone done reading Bs from Us
    #pragma unroll
    for (int rr2 = 0; rr2 < 4; rr2++) {
        int i = mbase + q * 4 + rr2;
        #pragma unroll
        for (int nt = 0; nt < NT; nt++)
            Us[i * LDM + nt * 16 + ln] = f2bf(acc[nt][rr2]);
    }
    __syncthreads();
    constexpr int CH = HOUT / 8;
    for (int c = tid; c < BM * CH; c += 512) {
        int row = c / CH, cc = c % CH;
        if (row < mcount) {
            uint4e v = *(const uint4e*)&Us[row * LDM + cc * 8];
            *(uint4e*)&ge.msg[(size_t)Pd[row] * HOUT + cc * 8] = v;
        }
    }
}

// weighted segment-sum of msg rows per dst + root base; optional relu+bf16.
// DOUBLE accumulation keeps results independent of the (nondeterministic)
// edge->slot assignment order. blockIdx.y selects the encoding bundle.
template <int H, bool RELU>
__global__ void k_reduce(RedArgs ra, const int* __restrict__ dstOff) {
    const RedEnc re = ra.e[blockIdx.y];
    int d = blockIdx.x * 4 + (threadIdx.x >> 6);
    if (d >= NN) return;
    int lane = threadIdx.x & 63;
    constexpr int HC = H / 4;
    constexpr int RPI = 64 / HC;
    int sub = lane / HC;
    int c4 = lane % HC;
    int j0 = dstOff[d], j1 = dstOff[d + 1];
    double a0 = 0.0, a1 = 0.0, a2 = 0.0, a3 = 0.0;
    for (int j = j0 + sub; j < j1; j += RPI) {
        float w = re.wD[j];
        uint2e v = *(const uint2e*)&re.msg[(size_t)j * H + c4 * 4];
        a0 += (double)(w * bfbits2f(v.x << 16));
        a1 += (double)(w * bfbits2f(v.x & 0xffff0000u));
        a2 += (double)(w * bfbits2f(v.y << 16));
        a3 += (double)(w * bfbits2f(v.y & 0xffff0000u));
    }
    #pragma unroll
    for (int ofs = 32; ofs >= HC; ofs >>= 1) {
        a0 += __shfl_down(a0, ofs); a1 += __shfl_down(a1, ofs);
        a2 += __shfl_down(a2, ofs); a3 += __shfl_down(a3, ofs);
    }
    if (lane < HC) {
        size_t o = (size_t)d * H + c4 * 4;
        float v0 = re.base[o] + (float)a0, v1 = re.base[o + 1] + (float)a1;
        float v2 = re.base[o + 2] + (float)a2, v3 = re.base[o + 3] + (float)a3;
        if (RELU) {
            v0 = fmaxf(v0, 0.f); v1 = fmaxf(v1, 0.f);
            v2 = fmaxf(v2, 0.f); v3 = fmaxf(v3, 0.f);
        }
        re.base[o] = v0; re.base[o + 1] = v1; re.base[o + 2] = v2; re.base[o + 3] = v3;
        if (RELU) {
            re.bfout[o] = f2bf(v0); re.bfout[o + 1] = f2bf(v1);
            re.bfout[o + 2] = f2bf(v2); re.bfout[o + 3] = f2bf(v3);
        }
    }
}

// column partial sums of x2_o -> part[block][32] (plain stores, deterministic)
__global__ void k_mean(const float* __restrict__ x2o, float* __restrict__ part) {
    __shared__ float s[256];
    int t = threadIdx.x; int hh = t & 31; int g = t >> 5;
    float acc = 0.f;
    for (int n = blockIdx.x * 8 + g; n < NN; n += gridDim.x * 8)
        acc += x2o[(size_t)n * 32 + hh];
    s[t] = acc;
    __syncthreads();
    if (t < 32) {
        float v = 0.f;
        for (int gg = 0; gg < 8; gg++) v += s[gg * 32 + t];
        part[blockIdx.x * 32 + t] = v;
    }
}

// deterministic final column sum: csum[c] = sum_b part[b][c] in fixed order
__global__ void k_csum(const float* __restrict__ part, float* __restrict__ csum) {
    int t = threadIdx.x;
    if (t < 32) {
        double a = 0.0;
        for (int b = 0; b < 256; b++) a += (double)part[b * 32 + t];
        csum[t] = (float)a;
    }
}

// c = sigmoid(csum/N); v = disc_W @ c; bilinear scores
__global__ void k_disc(const float* __restrict__ x2o, const float* __restrict__ x2a,
                       const float* __restrict__ x2aa, const float* __restrict__ csum,
                       const float* __restrict__ discW, const float* __restrict__ discb,
                       float* ret_os, float* ret_osa) {
    __shared__ float c[32], v[32];
    int t = threadIdx.x;
    if (t < 32) c[t] = 1.f / (1.f + expf(-csum[t] * (1.f / NN)));
    __syncthreads();
    if (t < 32) {
        float a = 0.f;
        for (int j = 0; j < 32; j++) a += discW[t * 32 + j] * c[j];
        v[t] = a;
    }
    __syncthreads();
    float db = discb[0];
    int n = blockIdx.x * 256 + t;
    if (n < NN) {
        float s1 = 0.f, s2 = 0.f, s3 = 0.f;
        for (int j = 0; j < 32; j++) {
            float vj = v[j];
            s1 += x2o[(size_t)n * 32 + j] * vj;
            s2 += x2a[(size_t)n * 32 + j] * vj;
            s3 += x2aa[(size_t)n * 32 + j] * vj;
        }
        ret_os[n * 2] = s1 + db;  ret_os[n * 2 + 1] = s2 + db;
        ret_osa[n * 2] = s1 + db; ret_osa[n * 2 + 1] = s3 + db;
    }
}

// pair classifier as MFMA GEMM (K padded to 512, N padded to 80)
__launch_bounds__(256, 2)
__global__ void k_clsg(const float* __restrict__ h1o, const float* __restrict__ x2o,
                       const float* __restrict__ feat, const float* __restrict__ attt,
                       const int* __restrict__ idx,
                       const unsigned short* __restrict__ cwt,
                       const float* __restrict__ clsb, float* __restrict__ log_out) {
    constexpr int LDK = CLS_CK + 8;
    __shared__ unsigned short As[CLS_BM][LDK];
    __shared__ unsigned short Bs[CLS_N][LDK];
    __shared__ int nd[2][CLS_BM];

    int tid = threadIdx.x;
    int p0 = blockIdx.x * CLS_BM;
    if (tid < CLS_BM) {
        nd[0][tid] = idx[p0 + tid];
        nd[1][tid] = idx[BB + p0 + tid];
    }
    float a0 = attt[0], a1 = attt[1];

    const int wave = tid >> 6;
    const int lane = tid & 63;
    const int q = lane >> 4;
    const int ln = lane & 15;
    constexpr int NT = CLS_N / 16;
    const int mbase = wave * 16;

    floatx4 acc[NT];
    #pragma unroll
    for (int nt = 0; nt < NT; nt++) acc[nt] = floatx4{0.f, 0.f, 0.f, 0.f};

    for (int ch = 0; ch < CLS_K / CLS_CK; ch++) {
        int kbase = ch * CLS_CK;
        __syncthreads();
        for (int c = tid; c < CLS_N * CLS_CK / 8; c += 256) {
            int row = c / (CLS_CK / 8), cc = c % (CLS_CK / 8);
            *(uint4*)&Bs[row][cc * 8] = *(const uint4*)&cwt[(size_t)row * CLS_K + kbase + cc * 8];
        }
        for (int c = tid; c < CLS_BM * CLS_CK / 4; c += 256) {
            int row = c / (CLS_CK / 4);
            int j4 = (c % (CLS_CK / 4)) * 4;
            int j = kbase + j4;
            float4 v = {0.f, 0.f, 0.f, 0.f};
            if (j < 448) {
                int hseg = j / 224, jj = j % 224;
                int node = nd[hseg][row];
                if (jj < 64) {
                    v = *(const float4*)&h1o[(size_t)node * 64 + jj];
                    v.x *= a0; v.y *= a0; v.z *= a0; v.w *= a0;
                } else if (jj < 96) {
                    v = *(const float4*)&x2o[(size_t)node * 32 + (jj - 64)];
                    v.x *= a1; v.y *= a1; v.z *= a1; v.w *= a1;
                } else {
                    v = *(const float4*)&feat[(size_t)node * 128 + (jj - 96)];
                }
            }
            uint2 pk;
            pk.x = (unsigned)f2bf(v.x) | ((unsigned)f2bf(v.y) << 16);
            pk.y = (unsigned)f2bf(v.z) | ((unsigned)f2bf(v.w) << 16);
            *(uint2*)&As[row][j4] = pk;
        }
        __syncthreads();
        #pragma unroll
        for (int ks = 0; ks < CLS_CK / 32; ks++) {
            int kk = ks * 32 + q * 8;
            short8 af = *(const short8*)&As[mbase + ln][kk];
            #pragma unroll
            for (int nt = 0; nt < NT; nt++) {
                short8 bf = *(const short8*)&Bs[nt * 16 + ln][kk];
                acc[nt] = __builtin_amdgcn_mfma_f32_16x16x32_bf16(af, bf, acc[nt], 0, 0, 0);
            }
        }
    }

    #pragma unroll
    for (int rr2 = 0; rr2 < 4; rr2++) {
        int i = mbase + q * 4 + rr2;
        int pair = p0 + i;
        #pragma unroll
        for (int nt = 0; nt < NT; nt++) {
            int col = nt * 16 + ln;
            if (col < RR)
                log_out[(size_t)pair * RR + col] = acc[nt][rr2] + clsb[col];
        }
    }
}

extern "C" void kernel_launch(void* const* d_in, const int* in_sizes, int n_in,
                              void* d_out, int out_size, void* d_ws, size_t ws_size,
                              hipStream_t stream) {
    const float* x_o   = (const float*)d_in[0];
    const float* x_a   = (const float*)d_in[1];
    const float* feat  = (const float*)d_in[2];
    const float* W1    = (const float*)d_in[3];
    const float* root1 = (const float*)d_in[4];
    const float* b1    = (const float*)d_in[5];
    const float* W2    = (const float*)d_in[6];
    const float* root2 = (const float*)d_in[7];
    const float* b2    = (const float*)d_in[8];
    const float* attt  = (const float*)d_in[9];
    const float* discW = (const float*)d_in[10];
    const float* discb = (const float*)d_in[11];
    const float* clsW  = (const float*)d_in[12];
    const float* clsb  = (const float*)d_in[13];
    const int* ei      = (const int*)d_in[14];
    const int* et0     = (const int*)d_in[15];
    const int* et1     = (const int*)d_in[16];
    const int* idx     = (const int*)d_in[17];

    char* ws = (char*)d_ws;
    float* csum = (float*)(ws + OFF_CSUM);
    int* cntD  = (int*)(ws + OFF_CNTD);
    int* dstOff = (int*)(ws + OFF_DSTOFF);
    int* bh0   = (int*)(ws + OFF_BH0);
    int* bh1   = (int*)(ws + OFF_BH1);
    int* bb0   = (int*)(ws + OFF_BB0);
    int* bb1   = (int*)(ws + OFF_BB1);
    int* hT    = (int*)(ws + OFF_HT);
    int* offB0 = (int*)(ws + OFF_OFFB0);
    int* offB1 = (int*)(ws + OFF_OFFB1);
    int* tilB0 = (int*)(ws + OFF_TILB0);
    int* tilT0 = (int*)(ws + OFF_TILT0);
    int* tilB1 = (int*)(ws + OFF_TILB1);
    int* tilT1 = (int*)(ws + OFF_TILT1);
    int* slotE = (int*)(ws + OFF_SLOT);
    int* posD  = (int*)(ws + OFF_POSD);
    unsigned int* rdP = (unsigned int*)(ws + OFF_RDP);
    float* wD0 = (float*)(ws + OFF_WD0);
    float* wD1 = (float*)(ws + OFF_WD1);
    unsigned int* perm0 = (unsigned int*)(ws + OFF_PERM0);
    unsigned int* perm1 = (unsigned int*)(ws + OFF_PERM1);
    unsigned short* xob = (unsigned short*)(ws + OFF_XOB);
    unsigned short* xab = (unsigned short*)(ws + OFF_XAB);
    float* h1o  = (float*)(ws + OFF_H1);
    float* h1a  = h1o + (size_t)NN * HH1;
    float* h1aa = h1a + (size_t)NN * HH1;
    unsigned short* h1bo  = (unsigned short*)(ws + OFF_H1B);
    unsigned short* h1ba  = h1bo + (size_t)NN * HH1;
    unsigned short* h1baa = h1ba + (size_t)NN * HH1;
    float* x2a  = (float*)(ws + OFF_X2A);
    float* x2aa = (float*)(ws + OFF_X2AA);
    unsigned short* w1t = (unsigned short*)(ws + OFF_W1BT);
    unsigned short* w2t = (unsigned short*)(ws + OFF_W2BT);
    unsigned short* r1t = (unsigned short*)(ws + OFF_R1T);
    unsigned short* r2t = (unsigned short*)(ws + OFF_R2T);
    unsigned short* cwt = (unsigned short*)(ws + OFF_CWT);
    float* part = (float*)(ws + OFF_PART);
    unsigned short* msg = (unsigned short*)(ws + OFF_MSG);

    float* out = (float*)d_out;
    float* log_out = out + O_LOG;
    float* ret_os  = out + O_ROS;
    float* ret_osa = out + O_ROSA;
    float* x2o     = out + O_X2O;

    // how many msg buffers fit? (runtime-tiered so any ws_size still works)
    size_t availMsg = ws_size > OFF_MSG ? ws_size - OFF_MSG : MSG_B1;
    int nb1 = (availMsg >= 2 * MSG_B1) ? 2 : 1;
    int nb2 = (availMsg >= 3 * MSG_B2) ? 3 : (availMsg >= 2 * MSG_B2 ? 2 : 1);

    // 1) zero control block (csum + cntD) — ~80 KB
    hipMemsetAsync(ws, 0, ZERO_BYTES, stream);

    // 2) preprocessing: (octile,relation) bucket sort with packed metadata
    k_hist<<<GRID_PRE, 256, 0, stream>>>(ei, et0, et1, cntD, slotE, bh0, bh1,
                                         x_o, x_a, W1, W2, root1, root2, clsW,
                                         xob, xab, w1t, w2t, r1t, r2t, cwt);
    k_scanD<<<1, 256, 0, stream>>>(cntD, dstOff);
    k_post<<<2500, 256, 0, stream>>>(ei, et0, et1, dstOff, slotE, posD, rdP);
    k_scanB1<<<(2 * NB2 + 3) / 4, 256, 0, stream>>>(bh0, bh1, bb0, bb1, hT);
    k_scanB2<<<1, 256, 0, stream>>>(hT, offB0, offB1,
                                    tilB0, tilT0, tilB1, tilT1);
    k_fillB<<<NBH, 256, 0, stream>>>(ei, et0, et1, posD, offB0, offB1, bb0, bb1,
                                     perm0, perm1);
    k_wts<<<NN / 4, 256, 0, stream>>>(dstOff, rdP, wD0, wD1);

    // 3) layer 1: MFMA root GEMM + grouped (edge GEMM -> weighted reduce)
    {
        dim3 gb(NBT, 3);
        k_bgemm<FIN1, HH1><<<gb, 256, 0, stream>>>(xob, xab, xob, r1t, b1,
                                                   h1o, h1a, h1aa);
        const unsigned short* Xs[3] = {xob, xab, xob};
        float* Os[3] = {h1o, h1a, h1aa};
        unsigned short* Obs[3] = {h1bo, h1ba, h1baa};
        for (int e0 = 0; e0 < 3; ) {
            int g = 3 - e0 < nb1 ? 3 - e0 : nb1;
            GemmArgs ga{};
            RedArgs ra{};
            for (int j = 0; j < g; j++) {
                int enc = e0 + j;
                unsigned short* mb = msg + (size_t)j * EE * HH1;
                ga.e[j].X    = Xs[enc];
                ga.e[j].msg  = mb;
                ga.e[j].perm = enc == 2 ? perm1 : perm0;
                ga.e[j].offB = enc == 2 ? offB1 : offB0;
                ga.e[j].tilB = enc == 2 ? tilB1 : tilB0;
                ga.e[j].tilT = enc == 2 ? tilT1 : tilT0;
                ra.e[j].msg  = mb;
                ra.e[j].wD   = enc == 2 ? wD1 : wD0;
                ra.e[j].base = Os[enc];
                ra.e[j].bfout = Obs[enc];
            }
            k_gemm<FIN1, HH1><<<dim3(MAXT2, g), 512, 0, stream>>>(ga, w1t);
            k_reduce<HH1, true><<<dim3(NN / 4, g), 256, 0, stream>>>(ra, dstOff);
            e0 += g;
        }
    }

    // 4) layer 2: MFMA root GEMM + grouped (edge GEMM -> weighted reduce)
    {
        dim3 gb(NBT, 3);
        k_bgemm<HH1, HH2><<<gb, 256, 0, stream>>>(h1bo, h1ba, h1baa, r2t, b2,
                                                  x2o, x2a, x2aa);
        const unsigned short* Xs[3] = {h1bo, h1ba, h1baa};
        float* Os[3] = {x2o, x2a, x2aa};
        for (int e0 = 0; e0 < 3; ) {
            int g = 3 - e0 < nb2 ? 3 - e0 : nb2;
            GemmArgs ga{};
            RedArgs ra{};
            for (int j = 0; j < g; j++) {
                int enc = e0 + j;
                unsigned short* mb = msg + (size_t)j * EE * HH2;
                ga.e[j].X    = Xs[enc];
                ga.e[j].msg  = mb;
                ga.e[j].perm = enc == 2 ? perm1 : perm0;
                ga.e[j].offB = enc == 2 ? offB1 : offB0;
                ga.e[j].tilB = enc == 2 ? tilB1 : tilB0;
                ga.e[j].tilT = enc == 2 ? tilT1 : tilT0;
                ra.e[j].msg  = mb;
                ra.e[j].wD   = enc == 2 ? wD1 : wD0;
                ra.e[j].base = Os[enc];
                ra.e[j].bfout = nullptr;
            }
            k_gemm<HH1, HH2><<<dim3(MAXT2, g), 512, 0, stream>>>(ga, w2t);
            k_reduce<HH2, false><<<dim3(NN / 4, g), 256, 0, stream>>>(ra, dstOff);
            e0 += g;
        }
    }

    // 5) readout + discriminator + classifier
    k_mean<<<256, 256, 0, stream>>>(x2o, part);
    k_csum<<<1, 64, 0, stream>>>(part, csum);
    k_disc<<<(NN + 255) / 256, 256, 0, stream>>>(x2o, x2a, x2aa, csum, discW, discb,
                                                 ret_os, ret_osa);
    k_clsg<<<BB / CLS_BM, 256, 0, stream>>>(h1o, x2o, feat, attt, idx, cwt, clsb, log_out);
}